// Round 1
// 753.401 us; speedup vs baseline: 1.0154x; 1.0154x over previous
//
#include <hip/hip_runtime.h>

// Problem constants
#define BB 8
#define CC 256
#define HH 224
#define WW 224
#define OUTC 256
#define PLANE (HH*WW)            // 50176
#define LN_EPS 1e-5f

// d_out layout (fp32 elements): out_sparse, kept_feats, kept_coords, keep
#define OFF_FEATS  102760448     // B*C*H*W
#define OFF_COORDS 102793216     // + 8*16*256
#define OFF_KEEP   102793728     // + 8*16*4

// ws layout (floats)
#define WS_COARSE 0              // [8][16][256]  (b*16+n)*256+c
#define WS_MX     33152          // [8][4][224]

#define NV8 (BB*CC*HH*WW/8)      // 12845056 vec8 chunks in out_sparse

typedef float vf4 __attribute__((ext_vector_type(4)));

// ---------------- Kernel A: grid max-pool (b,c,gy) -> 4 cell maxes ----------
__global__ __launch_bounds__(448) void pool_kernel(const float* __restrict__ x,
                                                   float* __restrict__ coarse) {
    int blk = blockIdx.x;            // (b*256+c)*4 + gy
    int gy  = blk & 3;
    int bc  = blk >> 2;              // b*256+c
    int t   = threadIdx.x;
    int chunk = t % 56;              // float4 chunk within row (56*4 = 224 cols)
    int rowg  = t / 56;              // 0..7
    int gx    = chunk / 14;          // 14 chunks per 56-col cell

    const float* p = x + (size_t)bc * PLANE + (size_t)(gy * 56) * WW + chunk * 4;
    float m = -INFINITY;
#pragma unroll
    for (int it = 0; it < 7; ++it) {
        float4 v = *(const float4*)(p + (size_t)(it * 8 + rowg) * WW);
        m = fmaxf(m, fmaxf(fmaxf(v.x, v.y), fmaxf(v.z, v.w)));
    }
    __shared__ float red[512];
    red[gx * 128 + rowg * 14 + (chunk % 14)] = m;    // 112 live slots per gx
    if (t < 64) red[(t / 16) * 128 + 112 + (t % 16)] = -INFINITY;  // pad to 128
    __syncthreads();
    if (t < 256) {
        int w = t >> 6, lane = t & 63;               // wave w reduces cell gx=w
        float v = fmaxf(red[w * 128 + lane], red[w * 128 + 64 + lane]);
        for (int s = 32; s; s >>= 1) v = fmaxf(v, __shfl_down(v, s, 64));
        if (lane == 0) {
            int b = bc >> 8, c = bc & 255;
            coarse[(b * 16 + gy * 4 + w) * 256 + c] = v;
        }
    }
}

// ---- Kernel B (fused): importance/mask/keep/coords/mx + LayerNorm+Linear ---
// One block per batch b. Replaces the previous stats_kernel + proj_kernel:
// keeps mu/rstd/keep in LDS (no ws round-trip) and absorbs the 128-block
// proj launch into this one.
__global__ __launch_bounds__(256) void stats_proj_kernel(
        const float* __restrict__ coarse,
        const float* __restrict__ logit_th,
        const float* __restrict__ gamma,
        const float* __restrict__ beta,
        const float* __restrict__ wp,
        const float* __restrict__ bp,
        float* __restrict__ keep_out,
        float* __restrict__ coords_out,
        float* __restrict__ feats_out,
        float* __restrict__ mx) {
    int b = blockIdx.x;
    int t = threadIdx.x;
    int wave = t >> 6, lane = t & 63;               // 4 waves
    __shared__ float ssum[16 * 4], ssq[16 * 4];
    __shared__ float simp[16], smask[16], skeep[16], smu[16], srstd[16];
    __shared__ float sn[16][256];                   // normalized feats, 16 KB
    const float* cb = coarse + b * 4096;

    // per-cell channel sums (sum, sumsq)
    for (int n = 0; n < 16; ++n) {
        float f = cb[n * 256 + t];
        float s = f, q = f * f;
        for (int d = 32; d; d >>= 1) {
            s += __shfl_down(s, d, 64);
            q += __shfl_down(q, d, 64);
        }
        if (lane == 0) { ssum[n * 4 + wave] = s; ssq[n * 4 + wave] = q; }
    }
    __syncthreads();
    if (t < 16) {
        int n = t;
        float s = ssum[n * 4] + ssum[n * 4 + 1] + ssum[n * 4 + 2] + ssum[n * 4 + 3];
        float q = ssq[n * 4] + ssq[n * 4 + 1] + ssq[n * 4 + 2] + ssq[n * 4 + 3];
        simp[n] = sqrtf(q);                          // L2 norm over channels
        float mu  = s * (1.0f / 256.0f);
        float var = q * (1.0f / 256.0f) - mu * mu;   // biased var
        smu[n]   = mu;
        srstd[n] = rsqrtf(var + LN_EPS);
    }
    __syncthreads();
    if (t < 16) {
        int n = t;
        float mn = simp[0], mxv = simp[0];
        for (int k = 1; k < 16; ++k) { mn = fminf(mn, simp[k]); mxv = fmaxf(mxv, simp[k]); }
        float imp01 = (simp[n] - mn) / (mxv - mn + 1e-8f);
        float lt = logit_th[2];
        float th = 1.0f / (1.0f + expf(-lt));        // sigmoid(logit)
        float hard = (imp01 >= th) ? 1.0f : 0.0f;
        float soft = 1.0f / (1.0f + expf(-10.0f * (imp01 - th)));
        float mv = fmaxf((hard - soft) + soft, 0.0f);    // STE forward value
        float kp = (mv > 0.5f) ? 1.0f : 0.0f;
        smask[n] = mv;
        skeep[n] = kp;
        keep_out[b * 16 + n] = kp;
        int gy = n >> 2, gx = n & 3;
        float cx = (gx + 0.5f) * 0.25f;
        float cy = (gy + 0.5f) * 0.25f;
        float* co = coords_out + (b * 16 + n) * 4;
        co[0] = cx * kp;
        co[1] = cy * kp;
        co[2] = 0.25f * kp;
        co[3] = 0.25f * kp;
    }
    __syncthreads();
    // precompute x-interpolated mask rows: mx[b][p][j], p = mask row 0..3
    for (int k = t; k < 4 * WW; k += 256) {
        int p = k / WW, j = k % WW;
        float u = (j + 0.5f) * (1.0f / 56.0f) - 0.5f;    // half-pixel mapping
        float x0f = floorf(u);
        float fx = u - x0f;
        int x0 = (int)x0f;
        int x0c = min(max(x0, 0), 3);
        int x1c = min(x0 + 1, 3);                        // x0+1 >= 0 always
        float a = smask[p * 4 + x0c];
        float bq = smask[p * 4 + x1c];
        mx[(b * 4 + p) * WW + j] = a + fx * (bq - a);
    }
    // normalized features into LDS (same formula/order as before)
    for (int n = 0; n < 16; ++n) {
        float f = cb[n * 256 + t];
        float nv = (f - smu[n]) * srstd[n];
        sn[n][t] = nv * gamma[t] + beta[t];
    }
    __syncthreads();
    // proj: thread t = output channel; 16 accumulators (one per cell).
    // wp[c*256+t] loaded once per c, reused across all 16 cells; sn[n][c]
    // is an LDS broadcast (uniform address across the wave).
    float acc[16];
#pragma unroll
    for (int n = 0; n < 16; ++n) acc[n] = 0.0f;
    for (int c = 0; c < 256; ++c) {
        float wv = wp[c * 256 + t];
#pragma unroll
        for (int n = 0; n < 16; ++n) acc[n] += sn[n][c] * wv;
    }
    float bb = bp[t];
#pragma unroll
    for (int n = 0; n < 16; ++n)
        feats_out[(b * 16 + n) * 256 + t] = (acc[n] + bb) * skeep[n];
}

// ------------- Kernel C: out = x * bilinear-upsampled mask ------------------
// nt stores for out (never re-read) + nt loads for x (last consumer): keeps
// the L3-resident tail of x (left there by pool's forward pass) from being
// evicted by the 411 MB out-store stream, so the reversed read harvests it.
__global__ __launch_bounds__(256) void sparse_kernel(const float* __restrict__ x,
                                                     const float* __restrict__ mx,
                                                     float* __restrict__ out) {
    int gid0 = blockIdx.x * 256 + threadIdx.x;
    int gid  = (NV8 - 1) - gid0;                 // reversed: harvest L3-resident tail of x
    int j8  = gid % 28;                          // 28 vec8 per row
    int rem = gid / 28;
    int i   = rem % HH;
    int bc  = rem / HH;
    int b   = bc >> 8;

    float u   = (i + 0.5f) * (1.0f / 56.0f) - 0.5f;
    float y0f = floorf(u);
    float fy  = u - y0f;
    int y0  = (int)y0f;
    int y0c = min(max(y0, 0), 3);
    int y1c = min(y0 + 1, 3);

    const float* r0 = mx + (b * 4 + y0c) * WW + j8 * 8;
    const float* r1 = mx + (b * 4 + y1c) * WW + j8 * 8;
    vf4 a0 = *(const vf4*)(r0);
    vf4 a1 = *(const vf4*)(r0 + 4);
    vf4 b0 = *(const vf4*)(r1);
    vf4 b1 = *(const vf4*)(r1 + 4);

    float m0 = a0.x + fy * (b0.x - a0.x);
    float m1 = a0.y + fy * (b0.y - a0.y);
    float m2 = a0.z + fy * (b0.z - a0.z);
    float m3 = a0.w + fy * (b0.w - a0.w);
    float m4 = a1.x + fy * (b1.x - a1.x);
    float m5 = a1.y + fy * (b1.y - a1.y);
    float m6 = a1.z + fy * (b1.z - a1.z);
    float m7 = a1.w + fy * (b1.w - a1.w);

    size_t off = (size_t)gid * 8;
    bool nz = (m0 != 0.0f) | (m1 != 0.0f) | (m2 != 0.0f) | (m3 != 0.0f) |
              (m4 != 0.0f) | (m5 != 0.0f) | (m6 != 0.0f) | (m7 != 0.0f);
    if (!nz) {
        vf4 z = 0.0f;
        __builtin_nontemporal_store(z, (vf4*)(out + off));
        __builtin_nontemporal_store(z, (vf4*)(out + off + 4));
        return;
    }
    vf4 x0 = __builtin_nontemporal_load((const vf4*)(x + off));
    vf4 x1 = __builtin_nontemporal_load((const vf4*)(x + off + 4));
    vf4 o0; o0.x = x0.x * m0; o0.y = x0.y * m1; o0.z = x0.z * m2; o0.w = x0.w * m3;
    vf4 o1; o1.x = x1.x * m4; o1.y = x1.y * m5; o1.z = x1.z * m6; o1.w = x1.w * m7;
    __builtin_nontemporal_store(o0, (vf4*)(out + off));
    __builtin_nontemporal_store(o1, (vf4*)(out + off + 4));
}

extern "C" void kernel_launch(void* const* d_in, const int* in_sizes, int n_in,
                              void* d_out, int out_size, void* d_ws, size_t ws_size,
                              hipStream_t stream) {
    const float* x     = (const float*)d_in[0];
    const float* lt    = (const float*)d_in[1];
    const float* gamma = (const float*)d_in[2];
    const float* beta  = (const float*)d_in[3];
    const float* wp    = (const float*)d_in[4];
    const float* bp    = (const float*)d_in[5];
    float* out = (float*)d_out;
    float* ws  = (float*)d_ws;

    float* coarse = ws + WS_COARSE;
    float* mx     = ws + WS_MX;

    pool_kernel<<<BB * CC * 4, 448, 0, stream>>>(x, coarse);
    stats_proj_kernel<<<BB, 256, 0, stream>>>(coarse, lt, gamma, beta, wp, bp,
                                              out + OFF_KEEP, out + OFF_COORDS,
                                              out + OFF_FEATS, mx);
    sparse_kernel<<<NV8 / 256, 256, 0, stream>>>(x, mx, out);
}